// Round 7
// baseline (231.523 us; speedup 1.0000x reference)
//
#include <hip/hip_runtime.h>
#include <hip/hip_fp16.h>

#define LL 2048
#define BB 2
#define DD 1024
#define HH 16
#define DKK 64

typedef _Float16 h8 __attribute__((ext_vector_type(8)));
typedef _Float16 h4 __attribute__((ext_vector_type(4)));
typedef float f4 __attribute__((ext_vector_type(4)));
typedef float f16v __attribute__((ext_vector_type(16)));

// lgkm-only barrier (keeps prefetch global loads in flight across it)
#define BAR() do {                                              \
    asm volatile("s_waitcnt lgkmcnt(0)" ::: "memory");          \
    __builtin_amdgcn_s_barrier();                               \
    asm volatile("" ::: "memory");                              \
} while (0)

// async global->LDS, 16B per lane; LDS dest is wave-uniform base + lane*16
__device__ __forceinline__ void gload_lds16(const void* g, void* l) {
    __builtin_amdgcn_global_load_lds(
        (const __attribute__((address_space(1))) void*)g,
        (__attribute__((address_space(3))) void*)l, 16, 0, 0);
}

// single v_cvt_pkrtz_f16_f32 (builtin returns __fp16 vector type)
__device__ __forceinline__ unsigned pack2h(float a, float b) {
    union { __fp16 v __attribute__((ext_vector_type(2))); unsigned u; } x;
    x.v = __builtin_amdgcn_cvt_pkrtz(a, b);
    return x.u;
}

// ---------------------------------------------------------------------------
// Kernel 0: convert 7 arrays f32->f16: qin/kin/vin (4M each), wq/wk/wv/wo (1M).
// ---------------------------------------------------------------------------
__global__ __launch_bounds__(256) void cvt_all(
    const float* __restrict__ x0, const float* __restrict__ x1,
    const float* __restrict__ x2, const float* __restrict__ w0,
    const float* __restrict__ w1, const float* __restrict__ w2,
    const float* __restrict__ w3,
    _Float16* __restrict__ y0, _Float16* __restrict__ y1,
    _Float16* __restrict__ y2, _Float16* __restrict__ z0,
    _Float16* __restrict__ z1, _Float16* __restrict__ z2,
    _Float16* __restrict__ z3)
{
    const int sel = blockIdx.y;
    if (sel >= 3 && blockIdx.x >= 512) return;
    const float* src = (sel == 0) ? x0 : (sel == 1) ? x1 : (sel == 2) ? x2
                     : (sel == 3) ? w0 : (sel == 4) ? w1 : (sel == 5) ? w2 : w3;
    _Float16* dst = (sel == 0) ? y0 : (sel == 1) ? y1 : (sel == 2) ? y2
                  : (sel == 3) ? z0 : (sel == 4) ? z1 : (sel == 5) ? z2 : z3;
    const int i = (blockIdx.x * 256 + threadIdx.x) * 8;
    f4 a = *(const f4*)(src + i);
    f4 b = *(const f4*)(src + i + 4);
    h8 o = {(_Float16)a.x, (_Float16)a.y, (_Float16)a.z, (_Float16)a.w,
            (_Float16)b.x, (_Float16)b.y, (_Float16)b.z, (_Float16)b.w};
    *(h8*)(dst + i) = o;
}

// ---------------------------------------------------------------------------
// Kernel 1: QKV projections, m97 structure (global_load_lds + unpadded LDS).
//   mode 0: Q -> qh[head][l][dk] * (0.125 * log2e)   [attn uses exp2]
//   mode 1: K -> kh[head][l][dk]
//   mode 2: V -> vth[head][dk][l]
// ---------------------------------------------------------------------------
__global__ __launch_bounds__(256) void qkv_proj(
    const _Float16* __restrict__ xq, const _Float16* __restrict__ xk,
    const _Float16* __restrict__ xv,
    const _Float16* __restrict__ wq, const float* __restrict__ bq,
    const _Float16* __restrict__ wk, const float* __restrict__ bk,
    const _Float16* __restrict__ wv, const float* __restrict__ bv,
    _Float16* __restrict__ qh, _Float16* __restrict__ kh,
    _Float16* __restrict__ vth)
{
    const int mode = blockIdx.z;
    const _Float16* X    = (mode == 0) ? xq : (mode == 1) ? xk : xv;
    const _Float16* W    = (mode == 0) ? wq : (mode == 1) ? wk : wv;
    const float*    bias = (mode == 0) ? bq : (mode == 1) ? bk : bv;

    __shared__ alignas(16) _Float16 a_sm[128 * 32];
    __shared__ alignas(16) _Float16 b_sm[128 * 32];

    const int tid  = threadIdx.x;
    const int lane = tid & 63;
    const int wave = tid >> 6;
    const int wm = (wave & 1) * 64;
    const int wn = (wave >> 1) * 64;
    const int m0 = blockIdx.x * 128;
    const int n0 = blockIdx.y * 128;

    const int srow = tid >> 2;
    const int scol = (tid & 3) * 8;
    const int lds_base = wave * 512;

    f4 acc[4][4];
    #pragma unroll
    for (int i = 0; i < 4; i++)
        #pragma unroll
        for (int j = 0; j < 4; j++)
            #pragma unroll
            for (int r = 0; r < 4; r++) acc[i][j][r] = 0.f;

    const int fr = lane & 15;
    const int fk = (lane >> 4) * 8;

    for (int k0 = 0; k0 < DD; k0 += 32) {
        gload_lds16(X + (size_t)(m0 + srow) * DD + k0 + scol,       &a_sm[lds_base]);
        gload_lds16(X + (size_t)(m0 + 64 + srow) * DD + k0 + scol,  &a_sm[2048 + lds_base]);
        gload_lds16(W + (size_t)(n0 + srow) * DD + k0 + scol,       &b_sm[lds_base]);
        gload_lds16(W + (size_t)(n0 + 64 + srow) * DD + k0 + scol,  &b_sm[2048 + lds_base]);
        __syncthreads();
        h8 af[4], bfr[4];
        #pragma unroll
        for (int i = 0; i < 4; i++) af[i]  = *(const h8*)&a_sm[(wm + i * 16 + fr) * 32 + fk];
        #pragma unroll
        for (int j = 0; j < 4; j++) bfr[j] = *(const h8*)&b_sm[(wn + j * 16 + fr) * 32 + fk];
        #pragma unroll
        for (int i = 0; i < 4; i++)
            #pragma unroll
            for (int j = 0; j < 4; j++)
                acc[i][j] = __builtin_amdgcn_mfma_f32_16x16x32_f16(af[i], bfr[j], acc[i][j], 0, 0, 0);
        __syncthreads();
    }

    const int colc = lane & 15;
    const int rowb = (lane >> 4) * 4;
    #pragma unroll
    for (int i = 0; i < 4; i++) {
        #pragma unroll
        for (int j = 0; j < 4; j++) {
            const int nn = n0 + wn + j * 16 + colc;
            const float bval = bias[nn];
            #pragma unroll
            for (int reg = 0; reg < 4; reg++) {
                const int mm = m0 + wm + i * 16 + rowb + reg;
                float v = acc[i][j][reg] + bval;
                const int b = mm & 1, l = mm >> 1;
                const int h = nn >> 6, dk = nn & 63;
                const int head = b * HH + h;
                if (mode == 0) {
                    v *= 0.1803368801111243f;  // DK^-0.5 * log2(e)
                    qh[((size_t)head * LL + l) * DKK + dk] = (_Float16)v;
                } else if (mode == 1) {
                    kh[((size_t)head * LL + l) * DKK + dk] = (_Float16)v;
                } else {
                    vth[((size_t)head * DKK + dk) * LL + l] = (_Float16)v;
                }
            }
        }
    }
}

// ---------------------------------------------------------------------------
// Kernel 2: attention v4 — occupancy doubled (grid 1024, 4 blocks/CU).
// Block = (64 q-rows, head); wave = (q-strip = wave&1, s-half = wave>>1).
// Superstep = 128 s staged as TWO 64-s buffers; wave pair {0,1} consumes
// buffer 0, pair {2,3} buffer 1.  Scores transposed (S^T = K.Q^T), P built
// in-register via half-wave swap (no LDS round-trip).  Epilogue combines
// the two s-halves' O/lsum through the (then-free) staging LDS.
// ---------------------------------------------------------------------------
__global__ __launch_bounds__(256, 4) void attn(
    const _Float16* __restrict__ qh, const _Float16* __restrict__ kh,
    const _Float16* __restrict__ vth, _Float16* __restrict__ oh)
{
    const int head = blockIdx.y;
    const int q0   = blockIdx.x * 64;
    const int tid = threadIdx.x, lane = tid & 63, wave = tid >> 6;
    const int qs = wave & 1;        // q-strip
    const int sw = wave >> 1;       // s-half (buffer index)
    const int qw = q0 + qs * 32;

    // smem: k [2][64][72]h (18432 B) | vt [2][64][72]h (18432 B) = 36864 B
    // epilogue overlay: comb [2][32][64]f (16384 B) | lsp [2][32]f | inv [2][32]f
    __shared__ alignas(16) char smem[36864 + 512];
    _Float16* ksm  = (_Float16*)smem;
    _Float16* vtsm = (_Float16*)(smem + 18432);

    const int rq = lane & 31;
    const int hi = lane >> 5;
    const int kb = hi * 8;
    const int tid8 = tid * 8;

    const _Float16* khead  = kh  + (size_t)head * LL * DKK;
    const _Float16* vthead = vth + (size_t)head * DKK * LL;

    // Q strip 32x64 -> 4 B-frags for S^T: B[n=q=lane&31][k=hi*8+j]
    const _Float16* qbase = qh + ((size_t)head * LL + qw + rq) * DKK;
    h8 qa[4];
    #pragma unroll
    for (int kf = 0; kf < 4; kf++) qa[kf] = *(const h8*)(qbase + kf * 16 + kb);

    f16v o0, o1;
    #pragma unroll
    for (int r = 0; r < 16; r++) { o0[r] = 0.f; o1[r] = 0.f; }
    float lsum = 0.f;

    // stage superstep 0 (both 64-s buffers; 2 h8 per array per buffer/thread)
    #pragma unroll
    for (int b2 = 0; b2 < 2; b2++) {
        #pragma unroll
        for (int i = 0; i < 2; i++) {
            const int flat = i * 2048 + tid8;
            const int row = flat >> 6, col = flat & 63;
            *(h8*)&ksm[b2 * 4608 + row * 72 + col] =
                *(const h8*)(khead + (size_t)(b2 * 64 + row) * DKK + col);
            *(h8*)&vtsm[b2 * 4608 + row * 72 + col] =
                *(const h8*)(vthead + (size_t)row * LL + b2 * 64 + col);
        }
    }
    BAR();

    const int koff = sw * 4608;

    for (int it = 0; it < 16; ++it) {
        const int s1 = it * 128 + 128;
        const bool more = (s1 < LL);

        h8 kpre[2][2], vpre[2][2];
        if (more) {
            #pragma unroll
            for (int b2 = 0; b2 < 2; b2++) {
                #pragma unroll
                for (int i = 0; i < 2; i++) {
                    const int flat = i * 2048 + tid8;
                    const int row = flat >> 6, col = flat & 63;
                    kpre[b2][i] = *(const h8*)(khead + (size_t)(s1 + b2 * 64 + row) * DKK + col);
                    vpre[b2][i] = *(const h8*)(vthead + (size_t)row * LL + s1 + b2 * 64 + col);
                }
            }
        }

        // two 32-s tiles of this wave's 64-s chunk
        #pragma unroll
        for (int st = 0; st < 2; st++) {
            f16v sc;
            #pragma unroll
            for (int r = 0; r < 16; r++) sc[r] = 0.f;
            #pragma unroll
            for (int kf = 0; kf < 4; kf++) {
                h8 kf8 = *(const h8*)&ksm[koff + (st * 32 + rq) * 72 + kf * 16 + kb];
                sc = __builtin_amdgcn_mfma_f32_32x32x16_f16(kf8, qa[kf], sc, 0, 0, 0);
            }

            float p[16];
            #pragma unroll
            for (int r = 0; r < 16; r++) {
                p[r] = __builtin_amdgcn_exp2f(sc[r]);
                lsum += p[r];
            }
            unsigned own[4][2], part[4][2];
            #pragma unroll
            for (int g = 0; g < 4; g++) {
                own[g][0] = pack2h(p[4 * g],     p[4 * g + 1]);
                own[g][1] = pack2h(p[4 * g + 2], p[4 * g + 3]);
                part[g][0] = __shfl_xor(own[g][0], 32, 64);
                part[g][1] = __shfl_xor(own[g][1], 32, 64);
            }
            #pragma unroll
            for (int f = 0; f < 2; f++) {
                union { unsigned u[4]; h8 h; } pa;
                pa.u[0] = hi ? part[2 * f + 1][0] : own[2 * f][0];
                pa.u[1] = hi ? part[2 * f + 1][1] : own[2 * f][1];
                pa.u[2] = hi ? own[2 * f + 1][0]  : part[2 * f][0];
                pa.u[3] = hi ? own[2 * f + 1][1]  : part[2 * f][1];
                const int vcol = st * 32 + f * 16 + kb;
                h8 b0 = *(const h8*)&vtsm[koff + rq * 72 + vcol];
                h8 b1 = *(const h8*)&vtsm[koff + (32 + rq) * 72 + vcol];
                o0 = __builtin_amdgcn_mfma_f32_32x32x16_f16(pa.h, b0, o0, 0, 0, 0);
                o1 = __builtin_amdgcn_mfma_f32_32x32x16_f16(pa.h, b1, o1, 0, 0, 0);
            }
        }

        BAR();  // everyone done with this superstep's buffers
        if (more) {
            #pragma unroll
            for (int b2 = 0; b2 < 2; b2++) {
                #pragma unroll
                for (int i = 0; i < 2; i++) {
                    const int flat = i * 2048 + tid8;
                    const int row = flat >> 6, col = flat & 63;
                    *(h8*)&ksm[b2 * 4608 + row * 72 + col]  = kpre[b2][i];
                    *(h8*)&vtsm[b2 * 4608 + row * 72 + col] = vpre[b2][i];
                }
            }
            BAR();  // publish next superstep
        }
    }

    // fold half-wave partner (hi split of s within this wave's chunk)
    lsum += __shfl_xor(lsum, 32, 64);

    // cross-pair combine: waves 2,3 hand off to waves 0,1 via LDS overlay
    float* comb = (float*)smem;                 // [2][32][64]
    float* lsp  = (float*)(smem + 16384);       // [2][32]
    float* invp = (float*)(smem + 16640);       // [2][32]

    if (wave >= 2) {
        float* c = comb + qs * 2048;
        #pragma unroll
        for (int r = 0; r < 16; r++) {
            const int row = (r & 3) + 8 * (r >> 2) + 4 * hi;
            c[row * 64 + rq]      = o0[r];
            c[row * 64 + 32 + rq] = o1[r];
        }
        if (hi == 0) lsp[qs * 32 + rq] = lsum;
    }
    BAR();
    if (wave < 2) {
        lsum += lsp[qs * 32 + rq];
        invp[qs * 32 + rq] = 1.0f / lsum;       // hi halves write same value
        asm volatile("s_waitcnt lgkmcnt(0)" ::: "memory");
        const int b = head >> 4, h = head & 15;
        const float* c = comb + qs * 2048;
        #pragma unroll
        for (int r = 0; r < 16; r++) {
            const int row = (r & 3) + 8 * (r >> 2) + 4 * hi;
            const float inv = invp[qs * 32 + row];
            const int ql = qw + row;
            const size_t base = (size_t)(ql * BB + b) * DD + h * DKK;
            oh[base + rq]      = (_Float16)((o0[r] + c[row * 64 + rq]) * inv);
            oh[base + 32 + rq] = (_Float16)((o1[r] + c[row * 64 + 32 + rq]) * inv);
        }
    }
}

// ---------------------------------------------------------------------------
// Kernel 3: output projection, m97 structure, 64x128 tiles (grid 512).
// ---------------------------------------------------------------------------
__global__ __launch_bounds__(256) void out_proj(
    const _Float16* __restrict__ oh, const _Float16* __restrict__ wo,
    const float* __restrict__ bo, float* __restrict__ out)
{
    __shared__ alignas(16) _Float16 a_sm[64 * 32];
    __shared__ alignas(16) _Float16 b_sm[128 * 32];
    const int tid = threadIdx.x, lane = tid & 63, wave = tid >> 6;
    const int wm = (wave & 1) * 32, wn = (wave >> 1) * 64;
    const int m0 = blockIdx.x * 64, n0 = blockIdx.y * 128;

    const int srow = tid >> 2;
    const int scol = (tid & 3) * 8;
    const int lds_base = wave * 512;

    f4 acc[2][4];
    #pragma unroll
    for (int i = 0; i < 2; i++)
        #pragma unroll
        for (int j = 0; j < 4; j++)
            #pragma unroll
            for (int r = 0; r < 4; r++) acc[i][j][r] = 0.f;

    const int fr = lane & 15;
    const int fk = (lane >> 4) * 8;

    for (int k0 = 0; k0 < DD; k0 += 32) {
        gload_lds16(oh + (size_t)(m0 + srow) * DD + k0 + scol,      &a_sm[lds_base]);
        gload_lds16(wo + (size_t)(n0 + srow) * DD + k0 + scol,      &b_sm[lds_base]);
        gload_lds16(wo + (size_t)(n0 + 64 + srow) * DD + k0 + scol, &b_sm[2048 + lds_base]);
        __syncthreads();
        h8 af[2], bfr[4];
        #pragma unroll
        for (int i = 0; i < 2; i++) af[i]  = *(const h8*)&a_sm[(wm + i * 16 + fr) * 32 + fk];
        #pragma unroll
        for (int j = 0; j < 4; j++) bfr[j] = *(const h8*)&b_sm[(wn + j * 16 + fr) * 32 + fk];
        #pragma unroll
        for (int i = 0; i < 2; i++)
            #pragma unroll
            for (int j = 0; j < 4; j++)
                acc[i][j] = __builtin_amdgcn_mfma_f32_16x16x32_f16(af[i], bfr[j], acc[i][j], 0, 0, 0);
        __syncthreads();
    }

    const int colc = lane & 15;
    const int rowb = (lane >> 4) * 4;
    #pragma unroll
    for (int i = 0; i < 2; i++) {
        #pragma unroll
        for (int j = 0; j < 4; j++) {
            const int nn = n0 + wn + j * 16 + colc;
            const float bval = bo[nn];
            #pragma unroll
            for (int reg = 0; reg < 4; reg++) {
                const int mm = m0 + wm + i * 16 + rowb + reg;
                out[(size_t)mm * DD + nn] = acc[i][j][reg] + bval;
            }
        }
    }
}

extern "C" void kernel_launch(void* const* d_in, const int* in_sizes, int n_in,
                              void* d_out, int out_size, void* d_ws, size_t ws_size,
                              hipStream_t stream) {
    const float* qin = (const float*)d_in[0];
    const float* kin = (const float*)d_in[1];
    const float* vin = (const float*)d_in[2];
    const float* wq  = (const float*)d_in[3];
    const float* bq  = (const float*)d_in[4];
    const float* wk  = (const float*)d_in[5];
    const float* bk  = (const float*)d_in[6];
    const float* wv  = (const float*)d_in[7];
    const float* bv  = (const float*)d_in[8];
    const float* wo  = (const float*)d_in[9];
    const float* bo  = (const float*)d_in[10];

    const size_t seg = (size_t)32 * LL * DKK;  // 4,194,304 halves
    _Float16* qh  = (_Float16*)d_ws;
    _Float16* kh  = qh + seg;
    _Float16* vth = kh + seg;
    _Float16* oh  = vth + seg;
    _Float16* wqh = oh + seg;
    _Float16* wkh = wqh + (size_t)DD * DD;
    _Float16* wvh = wkh + (size_t)DD * DD;
    _Float16* woh = wvh + (size_t)DD * DD;
    _Float16* xqh = woh + (size_t)DD * DD;
    _Float16* xkh = xqh + seg;
    _Float16* xvh = xkh + seg;

    hipLaunchKernelGGL(cvt_all, dim3(2048, 7), dim3(256), 0, stream,
                       qin, kin, vin, wq, wk, wv, wo,
                       xqh, xkh, xvh, wqh, wkh, wvh, woh);
    hipLaunchKernelGGL(qkv_proj, dim3(32, 8, 3), dim3(256), 0, stream,
                       xqh, xkh, xvh, wqh, bq, wkh, bk, wvh, bv, qh, kh, vth);
    hipLaunchKernelGGL(attn, dim3(32, 32), dim3(256), 0, stream, qh, kh, vth, oh);
    hipLaunchKernelGGL(out_proj, dim3(64, 8), dim3(256), 0, stream, oh, woh,
                       bo, (float*)d_out);
}